// Round 5
// baseline (250.771 us; speedup 1.0000x reference)
//
#include <hip/hip_runtime.h>
#include <math.h>

#define NB 32            // batch
#define DET_BLOCKS 96    // 3 scales * 32 images (det-only blocks)
#define SEG_BLOCKS 2048  // seg-only blocks, 1024 contiguous quads each
#define TOTAL_BLOCKS (DET_BLOCKS + SEG_BLOCKS)

// ---------- math helpers (match reference semantics) ----------

__device__ __forceinline__ float bce_logits(float x, float y) {
    // max(x,0) - x*y + log1p(exp(-|x|))
    float a = fabsf(x);
    return fmaxf(x, 0.f) - x * y + __logf(1.f + __expf(-a));
}

__device__ __forceinline__ float focal_elt(float x, float t) {
    // t is exactly 0.0 or 1.0 (one-hot)
    float p = 1.f / (1.f + __expf(-x));
    float ce = bce_logits(x, t);
    float p_t = (t > 0.5f) ? p : (1.f - p);
    float a_t = (t > 0.5f) ? 0.25f : 0.75f;
    float om = 1.f - p_t;
    return a_t * om * om * ce;
}

// Block reduction for N floats, blockDim.x == 256 (4 waves of 64).
template <int N>
__device__ void blk_reduce_arr(float* v) {
    __shared__ float sm[N][4];
    int lane = threadIdx.x & 63;
    int wid  = threadIdx.x >> 6;
#pragma unroll
    for (int j = 0; j < N; j++) {
        float x = v[j];
#pragma unroll
        for (int off = 32; off > 0; off >>= 1) x += __shfl_down(x, off, 64);
        if (lane == 0) sm[j][wid] = x;
    }
    __syncthreads();
    if (threadIdx.x == 0) {
#pragma unroll
        for (int j = 0; j < N; j++) {
            float s = 0.f;
#pragma unroll
            for (int w = 0; w < 4; w++) s += sm[j][w];
            v[j] = s;
        }
    }
}

// ---------- fused: det (blocks 0..95) + seg channel-sequential (blocks 96..) ----------

__global__ __launch_bounds__(256) void fused_kernel(
        const float* __restrict__ seg_logits, const int* __restrict__ mask,
        const float* __restrict__ cls0, const float* __restrict__ cls1, const float* __restrict__ cls2,
        const float* __restrict__ reg0, const float* __restrict__ reg1, const float* __restrict__ reg2,
        const float* __restrict__ cen0, const float* __restrict__ cen1, const float* __restrict__ cen2,
        const float* __restrict__ boxes, const int* __restrict__ labels,
        float* __restrict__ segpart, float* __restrict__ detc) {

    // ===== det blocks: one (scale, image) each, then exit =====
    if (blockIdx.x < DET_BLOCKS) {
        const int s = blockIdx.x >> 5;   // 0..2
        const int b = blockIdx.x & 31;   // 0..31
        int Wd, shift, L; float stride;
        const float *cls, *reg, *cen;
        if (s == 0)      { Wd = 64; shift = 6; L = 4096; stride = 8.f;  cls = cls0; reg = reg0; cen = cen0; }
        else if (s == 1) { Wd = 32; shift = 5; L = 1024; stride = 16.f; cls = cls1; reg = reg1; cen = cen1; }
        else             { Wd = 16; shift = 4; L = 256;  stride = 32.f; cls = cls2; reg = reg2; cen = cen2; }

        __shared__ float sx0[20], sy0[20], sx1[20], sy1[20], sar[20];
        __shared__ int   slb[20];
        if (threadIdx.x < 20) {
            int k = threadIdx.x;
            const float* bb = boxes + (b * 20 + k) * 4;
            float cx = bb[0] * 512.f, cy = bb[1] * 512.f;
            float w  = bb[2] * 512.f, h  = bb[3] * 512.f;
            float x0 = cx - 0.5f * w, y0 = cy - 0.5f * h;
            float x1 = cx + 0.5f * w, y1 = cy + 0.5f * h;
            sx0[k] = x0; sy0[k] = y0; sx1[k] = x1; sy1[k] = y1;
            sar[k] = (x1 - x0) * (y1 - y0);
            slb[k] = labels[b * 20 + k];
        }
        __syncthreads();

        const float* clsb = cls + (size_t)b * 5 * L;
        const float* regb = reg + (size_t)b * 4 * L;
        const float* cenb = cen + (size_t)b * L;
        const float inv = 1.f / stride;

        float cls_s = 0.f, reg_s = 0.f, cen_s = 0.f, np = 0.f;
        for (int l = threadIdx.x; l < L; l += 256) {
            float lx = ((l & (Wd - 1)) + 0.5f) * stride;
            float ly = ((l >> shift)   + 0.5f) * stride;
            int bk = -1; float ba = INFINITY;
            float bl = 0.f, btp = 0.f, brr = 0.f, bbt = 0.f;
#pragma unroll
            for (int k = 0; k < 20; k++) {
                float li = lx - sx0[k], ti = ly - sy0[k];
                float ri = sx1[k] - lx, bi = sy1[k] - ly;
                float mn = fminf(fminf(li, ti), fminf(ri, bi));
                if (mn > 0.f && sar[k] < ba) {   // strict '<' == first-occurrence argmin
                    ba = sar[k]; bk = k;
                    bl = li; btp = ti; brr = ri; bbt = bi;
                }
            }
            int tl = (bk >= 0) ? slb[bk] : -1;
#pragma unroll
            for (int c = 0; c < 4; c++) {
                float x = clsb[(c + 1) * L + l];   // channel 0 dropped by reference
                cls_s += focal_elt(x, (c == tl) ? 1.f : 0.f);
            }
            if (bk >= 0) {
                float r0 = bl * inv, r1 = btp * inv, r2 = brr * inv, r3 = bbt * inv;
                float d0 = regb[0 * L + l] - r0;
                float d1 = regb[1 * L + l] - r1;
                float d2 = regb[2 * L + l] - r2;
                float d3 = regb[3 * L + l] - r3;
                float a0 = fabsf(d0), a1 = fabsf(d1), a2 = fabsf(d2), a3 = fabsf(d3);
                float sl = (a0 < 1.f ? 0.5f * d0 * d0 : a0 - 0.5f)
                         + (a1 < 1.f ? 0.5f * d1 * d1 : a1 - 0.5f)
                         + (a2 < 1.f ? 0.5f * d2 * d2 : a2 - 0.5f)
                         + (a3 < 1.f ? 0.5f * d3 * d3 : a3 - 0.5f);
                reg_s += 0.25f * sl;
                float mnlr = fminf(r0, r2), mxlr = fmaxf(r0, r2);
                float mntb = fminf(r1, r3), mxtb = fmaxf(r1, r3);
                float v = (mnlr / (mxlr + 1e-6f)) * (mntb / (mxtb + 1e-6f));
                v = fminf(fmaxf(v, 0.f), 1.f);
                float ct = sqrtf(v);
                cen_s += bce_logits(cenb[l], ct);
                np += 1.f;
            }
        }

        float v4[4] = {cls_s, reg_s, cen_s, np};
        blk_reduce_arr<4>(v4);
        if (threadIdx.x == 0) {
            float cls_l = v4[0] / (L * 4.f);
            float npos  = v4[3];
            float denom = fmaxf(npos, 1.f);
            float reg_l = (npos > 0.f) ? v4[1] / denom : 0.f;
            float cen_l = (npos > 0.f) ? v4[2] / denom : 0.f;
            detc[blockIdx.x] = (cls_l + reg_l + cen_l) * (1.f / (float)DET_BLOCKS);
        }
        return;
    }

    // ===== seg blocks: 1024 contiguous quads, channel-sequential =====
    // Mask loaded ONCE into registers; then 16 iterations (4 channels x 4 chunks),
    // each iteration = one contiguous float4 stream load. At any instant a wave
    // has a single active stream -> no 1MB-strided load tuples.
    const int HW  = 512 * 512;     // 262144 px per image
    const int QPI = HW / 4;        // 65536 quads per image (float4/int4 units)
    const int sblk = blockIdx.x - DET_BLOCKS;       // 0..2047
    const size_t qbase = (size_t)sblk * 1024;       // 64 blocks per image, never straddles
    const int b   = (int)(qbase >> 16);             // image index
    const int hw0 = (int)(qbase & 65535) + threadIdx.x;

    const int4* mb = (const int4*)(mask + (size_t)b * HW) + hw0;
    float mf[16];
#pragma unroll
    for (int i = 0; i < 4; i++) {
        int4 m = mb[i * 256];
        mf[4 * i + 0] = (float)m.x; mf[4 * i + 1] = (float)m.y;
        mf[4 * i + 2] = (float)m.z; mf[4 * i + 3] = (float)m.w;
    }

    const float4* xb = (const float4*)(seg_logits + (size_t)b * 4 * HW) + hw0;

    float4 cur = xb[0];              // (c=0, i=0)
    float acc = 0.f;
#pragma unroll
    for (int it = 0; it < 16; it++) {
        float4 nxt;
        if (it + 1 < 16) {
            const int cn = (it + 1) >> 2, in = (it + 1) & 3;
            nxt = xb[cn * QPI + in * 256];   // prefetch next contiguous chunk
        }
        const int i4 = (it & 3) * 4;
        acc += bce_logits(cur.x, mf[i4 + 0]) + bce_logits(cur.y, mf[i4 + 1])
             + bce_logits(cur.z, mf[i4 + 2]) + bce_logits(cur.w, mf[i4 + 3]);
        if (it + 1 < 16) cur = nxt;
    }

    float v[1] = {acc};
    blk_reduce_arr<1>(v);
    if (threadIdx.x == 0) segpart[sblk] = v[0];
}

// ---------- final combine: all terms pre-scaled, one accumulator ----------

__global__ __launch_bounds__(256) void final_kernel(
        const float* __restrict__ segpart, const float* __restrict__ detc,
        const float* __restrict__ cls_pred, const int* __restrict__ cls_target,
        float* __restrict__ out) {
    const float seg_scale = 1.f / 33554432.f;   // B*4*512*512 (2^-25, exact)
    const float cls_scale = 0.5f / 320.f;       // W_CLS / (B*10)
    float acc = 0.f;
    for (int i = threadIdx.x; i < SEG_BLOCKS; i += 256) acc += segpart[i] * seg_scale;
    if (threadIdx.x < DET_BLOCKS) acc += detc[threadIdx.x];
    for (int e = threadIdx.x; e < NB * 10; e += 256) {
        int i = e / 10, c = e - i * 10;
        acc += cls_scale * focal_elt(cls_pred[e], (cls_target[i] == c) ? 1.f : 0.f);
    }
    float v[1] = {acc};
    blk_reduce_arr<1>(v);
    if (threadIdx.x == 0) out[0] = v[0];
}

// ---------- launch ----------

extern "C" void kernel_launch(void* const* d_in, const int* in_sizes, int n_in,
                              void* d_out, int out_size, void* d_ws, size_t ws_size,
                              hipStream_t stream) {
    const float* seg_logits = (const float*)d_in[0];
    const int*   seg_mask   = (const int*)d_in[1];
    const float* cls0 = (const float*)d_in[2];
    const float* cls1 = (const float*)d_in[3];
    const float* cls2 = (const float*)d_in[4];
    const float* reg0 = (const float*)d_in[5];
    const float* reg1 = (const float*)d_in[6];
    const float* reg2 = (const float*)d_in[7];
    const float* cen0 = (const float*)d_in[8];
    const float* cen1 = (const float*)d_in[9];
    const float* cen2 = (const float*)d_in[10];
    const float* boxes  = (const float*)d_in[11];
    const int*   labels = (const int*)d_in[12];
    const float* cls_pred   = (const float*)d_in[13];
    const int*   cls_target = (const int*)d_in[14];

    float* ws      = (float*)d_ws;
    float* segpart = ws;                 // SEG_BLOCKS floats
    float* detc    = ws + SEG_BLOCKS;    // DET_BLOCKS floats

    fused_kernel<<<TOTAL_BLOCKS, 256, 0, stream>>>(seg_logits, seg_mask,
                                                   cls0, cls1, cls2,
                                                   reg0, reg1, reg2,
                                                   cen0, cen1, cen2,
                                                   boxes, labels, segpart, detc);
    final_kernel<<<1, 256, 0, stream>>>(segpart, detc, cls_pred, cls_target,
                                        (float*)d_out);
}

// Round 6
// 247.400 us; speedup vs baseline: 1.0136x; 1.0136x over previous
//
#include <hip/hip_runtime.h>
#include <math.h>

#define NB 32            // batch
#define DET_BLOCKS 96    // 3 scales * 32 images (det-only blocks)
#define SEG_BLOCKS 1024  // seg blocks, 2048 quads each
#define CHUNKS 8         // 8 chunks of 256 quads per seg block
#define TOTAL_BLOCKS (DET_BLOCKS + SEG_BLOCKS)

// ---------- math helpers (match reference semantics) ----------

__device__ __forceinline__ float bce_logits(float x, float y) {
    // max(x,0) - x*y + log1p(exp(-|x|))
    float a = fabsf(x);
    return fmaxf(x, 0.f) - x * y + __logf(1.f + __expf(-a));
}

__device__ __forceinline__ float focal_elt(float x, float t) {
    // t is exactly 0.0 or 1.0 (one-hot)
    float p = 1.f / (1.f + __expf(-x));
    float ce = bce_logits(x, t);
    float p_t = (t > 0.5f) ? p : (1.f - p);
    float a_t = (t > 0.5f) ? 0.25f : 0.75f;
    float om = 1.f - p_t;
    return a_t * om * om * ce;
}

// Block reduction for N floats, blockDim.x == 256 (4 waves of 64).
template <int N>
__device__ void blk_reduce_arr(float* v) {
    __shared__ float sm[N][4];
    int lane = threadIdx.x & 63;
    int wid  = threadIdx.x >> 6;
#pragma unroll
    for (int j = 0; j < N; j++) {
        float x = v[j];
#pragma unroll
        for (int off = 32; off > 0; off >>= 1) x += __shfl_down(x, off, 64);
        if (lane == 0) sm[j][wid] = x;
    }
    __syncthreads();
    if (threadIdx.x == 0) {
#pragma unroll
        for (int j = 0; j < N; j++) {
            float s = 0.f;
#pragma unroll
            for (int w = 0; w < 4; w++) s += sm[j][w];
            v[j] = s;
        }
    }
}

// async global -> LDS, 16B per lane; lds dest = wave-uniform base + lane*16
__device__ __forceinline__ void stage16(const void* g, void* l) {
    __builtin_amdgcn_global_load_lds((const unsigned int*)g, (unsigned int*)l,
                                     16, 0, 0);
}

// ---------- fused: det (blocks 0..95) + seg LDS-staged (blocks 96..) ----------

__global__ __launch_bounds__(256) void fused_kernel(
        const float* __restrict__ seg_logits, const int* __restrict__ mask,
        const float* __restrict__ cls0, const float* __restrict__ cls1, const float* __restrict__ cls2,
        const float* __restrict__ reg0, const float* __restrict__ reg1, const float* __restrict__ reg2,
        const float* __restrict__ cen0, const float* __restrict__ cen1, const float* __restrict__ cen2,
        const float* __restrict__ boxes, const int* __restrict__ labels,
        float* __restrict__ segpart, float* __restrict__ detc) {

    // 2 buffers x (mask 256 int4 + 4 channels x 256 float4) = 2 x 20 KB
    __shared__ float4 sbuf[2][5 * 256];

    // ===== det blocks: one (scale, image) each, then exit =====
    if (blockIdx.x < DET_BLOCKS) {
        const int s = blockIdx.x >> 5;   // 0..2
        const int b = blockIdx.x & 31;   // 0..31
        int Wd, shift, L; float stride;
        const float *cls, *reg, *cen;
        if (s == 0)      { Wd = 64; shift = 6; L = 4096; stride = 8.f;  cls = cls0; reg = reg0; cen = cen0; }
        else if (s == 1) { Wd = 32; shift = 5; L = 1024; stride = 16.f; cls = cls1; reg = reg1; cen = cen1; }
        else             { Wd = 16; shift = 4; L = 256;  stride = 32.f; cls = cls2; reg = reg2; cen = cen2; }

        __shared__ float sx0[20], sy0[20], sx1[20], sy1[20], sar[20];
        __shared__ int   slb[20];
        if (threadIdx.x < 20) {
            int k = threadIdx.x;
            const float* bb = boxes + (b * 20 + k) * 4;
            float cx = bb[0] * 512.f, cy = bb[1] * 512.f;
            float w  = bb[2] * 512.f, h  = bb[3] * 512.f;
            float x0 = cx - 0.5f * w, y0 = cy - 0.5f * h;
            float x1 = cx + 0.5f * w, y1 = cy + 0.5f * h;
            sx0[k] = x0; sy0[k] = y0; sx1[k] = x1; sy1[k] = y1;
            sar[k] = (x1 - x0) * (y1 - y0);
            slb[k] = labels[b * 20 + k];
        }
        __syncthreads();

        const float* clsb = cls + (size_t)b * 5 * L;
        const float* regb = reg + (size_t)b * 4 * L;
        const float* cenb = cen + (size_t)b * L;
        const float inv = 1.f / stride;

        float cls_s = 0.f, reg_s = 0.f, cen_s = 0.f, np = 0.f;
        for (int l = threadIdx.x; l < L; l += 256) {
            float lx = ((l & (Wd - 1)) + 0.5f) * stride;
            float ly = ((l >> shift)   + 0.5f) * stride;
            int bk = -1; float ba = INFINITY;
            float bl = 0.f, btp = 0.f, brr = 0.f, bbt = 0.f;
#pragma unroll
            for (int k = 0; k < 20; k++) {
                float li = lx - sx0[k], ti = ly - sy0[k];
                float ri = sx1[k] - lx, bi = sy1[k] - ly;
                float mn = fminf(fminf(li, ti), fminf(ri, bi));
                if (mn > 0.f && sar[k] < ba) {   // strict '<' == first-occurrence argmin
                    ba = sar[k]; bk = k;
                    bl = li; btp = ti; brr = ri; bbt = bi;
                }
            }
            int tl = (bk >= 0) ? slb[bk] : -1;
#pragma unroll
            for (int c = 0; c < 4; c++) {
                float x = clsb[(c + 1) * L + l];   // channel 0 dropped by reference
                cls_s += focal_elt(x, (c == tl) ? 1.f : 0.f);
            }
            if (bk >= 0) {
                float r0 = bl * inv, r1 = btp * inv, r2 = brr * inv, r3 = bbt * inv;
                float d0 = regb[0 * L + l] - r0;
                float d1 = regb[1 * L + l] - r1;
                float d2 = regb[2 * L + l] - r2;
                float d3 = regb[3 * L + l] - r3;
                float a0 = fabsf(d0), a1 = fabsf(d1), a2 = fabsf(d2), a3 = fabsf(d3);
                float sl = (a0 < 1.f ? 0.5f * d0 * d0 : a0 - 0.5f)
                         + (a1 < 1.f ? 0.5f * d1 * d1 : a1 - 0.5f)
                         + (a2 < 1.f ? 0.5f * d2 * d2 : a2 - 0.5f)
                         + (a3 < 1.f ? 0.5f * d3 * d3 : a3 - 0.5f);
                reg_s += 0.25f * sl;
                float mnlr = fminf(r0, r2), mxlr = fmaxf(r0, r2);
                float mntb = fminf(r1, r3), mxtb = fmaxf(r1, r3);
                float v = (mnlr / (mxlr + 1e-6f)) * (mntb / (mxtb + 1e-6f));
                v = fminf(fmaxf(v, 0.f), 1.f);
                float ct = sqrtf(v);
                cen_s += bce_logits(cenb[l], ct);
                np += 1.f;
            }
        }

        float v4[4] = {cls_s, reg_s, cen_s, np};
        blk_reduce_arr<4>(v4);
        if (threadIdx.x == 0) {
            float cls_l = v4[0] / (L * 4.f);
            float npos  = v4[3];
            float denom = fmaxf(npos, 1.f);
            float reg_l = (npos > 0.f) ? v4[1] / denom : 0.f;
            float cen_l = (npos > 0.f) ? v4[2] / denom : 0.f;
            detc[blockIdx.x] = (cls_l + reg_l + cen_l) * (1.f / (float)DET_BLOCKS);
        }
        return;
    }

    // ===== seg blocks: 2048 quads via double-buffered global_load_lds =====
    const int HW  = 512 * 512;     // px per image
    const int QPI = HW / 4;        // 65536 quads per image (float4/int4 units)
    const int sblk = blockIdx.x - DET_BLOCKS;     // 0..1023
    const size_t qbase = (size_t)sblk * 2048;     // 32 blocks per image, no straddle
    const int b  = (int)(qbase >> 16);            // image index
    const int qs = (int)(qbase & 65535);          // start quad within image
    const int t  = threadIdx.x;

    const int4*   mq = (const int4*)(mask + (size_t)b * HW) + qs;          // mask quads
    const float4* xq = (const float4*)(seg_logits + (size_t)b * 4 * HW) + qs;

    // wave-uniform LDS byte offset for this wave's 64 lanes (forced to SGPR)
    const int wbyte = __builtin_amdgcn_readfirstlane((t >> 6) << 10);      // w * 1024 B

    // stage chunk j into buffer p: 5 async dwordx4 per thread (1 per wave-section)
    #define STAGE(p, j) do {                                                         \
        char* base = (char*)&sbuf[p][0];                                             \
        stage16(mq + (j) * 256 + t,           base + 0 * 4096 + wbyte);              \
        stage16(xq + 0 * QPI + (j) * 256 + t, base + 1 * 4096 + wbyte);              \
        stage16(xq + 1 * QPI + (j) * 256 + t, base + 2 * 4096 + wbyte);              \
        stage16(xq + 2 * QPI + (j) * 256 + t, base + 3 * 4096 + wbyte);              \
        stage16(xq + 3 * QPI + (j) * 256 + t, base + 4 * 4096 + wbyte);              \
    } while (0)

    STAGE(0, 0);

    float acc = 0.f;
    for (int j = 0; j < CHUNKS; j++) {
        const int p = j & 1;
        if (j + 1 < CHUNKS) {
            STAGE(p ^ 1, j + 1);
            asm volatile("s_waitcnt vmcnt(5)" ::: "memory");   // chunk j staged
        } else {
            asm volatile("s_waitcnt vmcnt(0)" ::: "memory");
        }
        __syncthreads();                                        // all waves' stages done

        const int4   m  = ((const int4*)&sbuf[p][0])[t];
        const float4 x0 = sbuf[p][1 * 256 + t];
        const float4 x1 = sbuf[p][2 * 256 + t];
        const float4 x2 = sbuf[p][3 * 256 + t];
        const float4 x3 = sbuf[p][4 * 256 + t];
        const float t0 = (float)m.x, t1 = (float)m.y, t2 = (float)m.z, t3 = (float)m.w;
        acc += bce_logits(x0.x, t0) + bce_logits(x0.y, t1)
             + bce_logits(x0.z, t2) + bce_logits(x0.w, t3);
        acc += bce_logits(x1.x, t0) + bce_logits(x1.y, t1)
             + bce_logits(x1.z, t2) + bce_logits(x1.w, t3);
        acc += bce_logits(x2.x, t0) + bce_logits(x2.y, t1)
             + bce_logits(x2.z, t2) + bce_logits(x2.w, t3);
        acc += bce_logits(x3.x, t0) + bce_logits(x3.y, t1)
             + bce_logits(x3.z, t2) + bce_logits(x3.w, t3);

        __syncthreads();   // everyone done reading buf p before it's re-staged
    }
    #undef STAGE

    float v[1] = {acc};
    blk_reduce_arr<1>(v);
    if (threadIdx.x == 0) segpart[sblk] = v[0];
}

// ---------- final combine: all terms pre-scaled, one accumulator ----------

__global__ __launch_bounds__(256) void final_kernel(
        const float* __restrict__ segpart, const float* __restrict__ detc,
        const float* __restrict__ cls_pred, const int* __restrict__ cls_target,
        float* __restrict__ out) {
    const float seg_scale = 1.f / 33554432.f;   // B*4*512*512 (2^-25, exact)
    const float cls_scale = 0.5f / 320.f;       // W_CLS / (B*10)
    float acc = 0.f;
    for (int i = threadIdx.x; i < SEG_BLOCKS; i += 256) acc += segpart[i] * seg_scale;
    if (threadIdx.x < DET_BLOCKS) acc += detc[threadIdx.x];
    for (int e = threadIdx.x; e < NB * 10; e += 256) {
        int i = e / 10, c = e - i * 10;
        acc += cls_scale * focal_elt(cls_pred[e], (cls_target[i] == c) ? 1.f : 0.f);
    }
    float v[1] = {acc};
    blk_reduce_arr<1>(v);
    if (threadIdx.x == 0) out[0] = v[0];
}

// ---------- launch ----------

extern "C" void kernel_launch(void* const* d_in, const int* in_sizes, int n_in,
                              void* d_out, int out_size, void* d_ws, size_t ws_size,
                              hipStream_t stream) {
    const float* seg_logits = (const float*)d_in[0];
    const int*   seg_mask   = (const int*)d_in[1];
    const float* cls0 = (const float*)d_in[2];
    const float* cls1 = (const float*)d_in[3];
    const float* cls2 = (const float*)d_in[4];
    const float* reg0 = (const float*)d_in[5];
    const float* reg1 = (const float*)d_in[6];
    const float* reg2 = (const float*)d_in[7];
    const float* cen0 = (const float*)d_in[8];
    const float* cen1 = (const float*)d_in[9];
    const float* cen2 = (const float*)d_in[10];
    const float* boxes  = (const float*)d_in[11];
    const int*   labels = (const int*)d_in[12];
    const float* cls_pred   = (const float*)d_in[13];
    const int*   cls_target = (const int*)d_in[14];

    float* ws      = (float*)d_ws;
    float* segpart = ws;                 // SEG_BLOCKS floats
    float* detc    = ws + SEG_BLOCKS;    // DET_BLOCKS floats

    fused_kernel<<<TOTAL_BLOCKS, 256, 0, stream>>>(seg_logits, seg_mask,
                                                   cls0, cls1, cls2,
                                                   reg0, reg1, reg2,
                                                   cen0, cen1, cen2,
                                                   boxes, labels, segpart, detc);
    final_kernel<<<1, 256, 0, stream>>>(segpart, detc, cls_pred, cls_target,
                                        (float*)d_out);
}